// Round 2
// baseline (107.322 us; speedup 1.0000x reference)
//
#include <hip/hip_runtime.h>
#include <math.h>

#define TEMP_F 0.07f
#define NCON 20
#define LDIM 512
#define NROWS 32768
#define NSEL 16384

// ws layout (floats):
// [0 .. NROWS)            norm[r]    = ||hg_row r||_2
// [NROWS .. 2*NROWS)      dot_sz[r]  = <hg_row r, ebar_sz>
// [2*NROWS .. 3*NROWS)    dot_nsz[r] = <hg_row r, ebar_nsz>

__device__ inline float dot4(float4 a, float4 b) {
    return a.x * b.x + a.y * b.y + a.z * b.z + a.w * b.w;
}

// Grid-stride: 1024 blocks x 256 threads, 1 wave per row per iteration.
// Each block computes the two e_bar vectors into LDS once (all_emb is 40 KB,
// L2-resident; 1024 recomputes ~ 20 MB L2 traffic, ~1 us) — this removes the
// separate 1-block prep kernel (~4 us of pure latency) from the serial chain.
__global__ __launch_bounds__(256) void rowstats_kernel(const float* __restrict__ hg,
                                                       const float* __restrict__ all_emb,
                                                       const int* __restrict__ Psz,
                                                       const int* __restrict__ Pnsz,
                                                       float* __restrict__ ws,
                                                       float* __restrict__ out) {
    __shared__ float ebs[LDIM];
    __shared__ float ebn[LDIM];
    const int t = threadIdx.x;

    for (int j = t; j < LDIM; j += 256) {
        float s1 = 0.f, s2 = 0.f;
#pragma unroll
        for (int k = 0; k < 5; ++k) {
            s1 += all_emb[Psz[k]  * LDIM + j];
            s2 += all_emb[Pnsz[k] * LDIM + j];
        }
        ebs[j] = s1 * 0.2f;   // mean over 5 (duplicates counted, matches ref)
        ebn[j] = s2 * 0.2f;
    }
    if (blockIdx.x == 0 && t == 0) out[0] = 0.f;  // d_out poisoned 0xAA each call
    __syncthreads();

    const int lane = t & 63;
    const int w    = t >> 6;

    const float4 es0 = ((const float4*)ebs)[lane * 2];
    const float4 es1 = ((const float4*)ebs)[lane * 2 + 1];
    const float4 en0 = ((const float4*)ebn)[lane * 2];
    const float4 en1 = ((const float4*)ebn)[lane * 2 + 1];

    float* __restrict__ norm_o = ws;
    float* __restrict__ dsz_o  = ws + NROWS;
    float* __restrict__ dnsz_o = ws + 2 * NROWS;

    const int stride = gridDim.x * 4;  // waves in grid
    for (int row = blockIdx.x * 4 + w; row < NROWS; row += stride) {
        const float4* rp = (const float4*)hg + (size_t)row * (LDIM / 4) + lane * 2;
        float4 a0 = rp[0];
        float4 a1 = rp[1];

        float ss   = dot4(a0, a0) + dot4(a1, a1);
        float dsz  = dot4(a0, es0) + dot4(a1, es1);
        float dnsz = dot4(a0, en0) + dot4(a1, en1);

#pragma unroll
        for (int off = 32; off; off >>= 1) {
            ss   += __shfl_xor(ss, off);
            dsz  += __shfl_xor(dsz, off);
            dnsz += __shfl_xor(dnsz, off);
        }
        if (lane == 0) {
            norm_o[row] = sqrtf(ss);
            dsz_o[row]  = dsz;
            dnsz_o[row] = dnsz;
        }
    }
}

// gridDim = (64, 2): 64*256 = 16384 threads per branch, branch = blockIdx.y
__global__ __launch_bounds__(256) void branch_kernel(const float* __restrict__ sim,
                                                     const int* __restrict__ sz_idx,
                                                     const int* __restrict__ nsz_idx,
                                                     const int* __restrict__ Psz,
                                                     const int* __restrict__ Pnsz,
                                                     const float* __restrict__ ws,
                                                     float* __restrict__ out) {
    const int b = blockIdx.y;
    const int* __restrict__ idx = (b == 0) ? sz_idx : nsz_idx;
    const int* __restrict__ P   = (b == 0) ? Psz : Pnsz;

    unsigned mask = (1u << NCON) - 1u;
#pragma unroll
    for (int k = 0; k < 5; ++k) mask &= ~(1u << P[k]);

    const float* __restrict__ norm = ws;
    const float* __restrict__ dot  = ws + NROWS + b * NROWS;

    const int i = blockIdx.x * blockDim.x + threadIdx.x;  // < 16384 exactly
    const int r = idx[i];

    // 20-float sim row, 80-byte aligned -> 5 x float4
    const float4* srow = (const float4*)(sim + (size_t)r * NCON);
    float4 v0 = srow[0], v1 = srow[1], v2 = srow[2], v3 = srow[3], v4 = srow[4];
    float s[NCON] = {v0.x, v0.y, v0.z, v0.w, v1.x, v1.y, v1.z, v1.w,
                     v2.x, v2.y, v2.z, v2.w, v3.x, v3.y, v3.z, v3.w,
                     v4.x, v4.y, v4.z, v4.w};

    const float invT = 1.0f / TEMP_F;
    float den = 0.f;
#pragma unroll
    for (int j = 0; j < NCON; ++j)
        if (mask & (1u << j)) den += expf(s[j] * invT);

    float term = logf(den) - dot[r] * invT / fmaxf(norm[r], 1e-12f);

    // block reduction: wave shuffle then LDS across 4 waves
    __shared__ float red[4];
#pragma unroll
    for (int off = 32; off; off >>= 1) term += __shfl_xor(term, off);
    const int lane = threadIdx.x & 63;
    const int w = threadIdx.x >> 6;
    if (lane == 0) red[w] = term;
    __syncthreads();
    if (threadIdx.x == 0) {
        float bsum = red[0] + red[1] + red[2] + red[3];
        atomicAdd(out, bsum * (1.0f / NSEL));
    }
}

extern "C" void kernel_launch(void* const* d_in, const int* in_sizes, int n_in,
                              void* d_out, int out_size, void* d_ws, size_t ws_size,
                              hipStream_t stream) {
    const float* hg       = (const float*)d_in[0];
    const float* hg_corr  = (const float*)d_in[1];
    const float* all_emb  = (const float*)d_in[2];
    const int*   sz_idx   = (const int*)d_in[3];
    const int*   nsz_idx  = (const int*)d_in[4];
    const int*   Psz      = (const int*)d_in[5];
    const int*   Pnsz     = (const int*)d_in[6];
    float* out = (float*)d_out;
    float* ws  = (float*)d_ws;

    rowstats_kernel<<<1024, 256, 0, stream>>>(hg, all_emb, Psz, Pnsz, ws, out);
    dim3 g(64, 2);
    branch_kernel<<<g, 256, 0, stream>>>(hg_corr, sz_idx, nsz_idx, Psz, Pnsz, ws, out);
}